// Round 6
// baseline (122.670 us; speedup 1.0000x reference)
//
#include <hip/hip_runtime.h>

// B=4, M=8, N=128, D=32, K=2D=H=64
#define BMC 32
#define NNC 128
#define DDC 32
#define KKC 64
constexpr int ND = NNC * DDC;   // 4096
constexpr int NK = NNC * KKC;   // 8192
#define SMALLV 1e-8f

__device__ __forceinline__ float gelu_f(float v) {
    // tanh-gelu folded: gelu(v) = v - v * rcp(1 + exp2(v*(a*v^2+b)))
    float v2 = v * v;
    float p  = fmaf(0.1029432f, v2, 2.3022082f);
    float e  = __builtin_amdgcn_exp2f(v * p);
    float r  = __builtin_amdgcn_rcpf(e + 1.0f);
    return fmaf(-v, r, v);
}

// ---------------------------------------------------------------------------
// Kernel 1: fused stats + MLP1 + A1/A2 + out pre-init (residual + b3).
// Grid = bm(32) x nt(16) = 512 x 256.
// ---------------------------------------------------------------------------
__global__ __launch_bounds__(256) void mlp_kernel(
    const float* __restrict__ x, const float* __restrict__ x_size,
    const float* __restrict__ W1a, const float* __restrict__ b1a,
    const float* __restrict__ W1b, const float* __restrict__ b1b,
    const float* __restrict__ W2a, const float* __restrict__ b2a,
    const float* __restrict__ W2b, const float* __restrict__ b2b,
    const float* __restrict__ w3, const float* __restrict__ b3,
    float* __restrict__ x1g, float* __restrict__ A1g, float* __restrict__ A2t,
    float* __restrict__ v2g, float* __restrict__ c3g, float* __restrict__ out)
{
    __shared__ float sW1a[DDC * KKC];   // 8 KB
    __shared__ float sW1b[KKC * DDC];   // 8 KB
    __shared__ float sW2a[DDC * KKC];   // 8 KB
    __shared__ float sXn[8 * DDC];
    __shared__ float sH[8 * KKC];
    __shared__ float sX1[8 * DDC];
    __shared__ float sB1a[KKC], sB2a[KKC], sB1b[DDC];
    __shared__ float sAny[NNC];
    __shared__ float sRed[4];

    const int t  = threadIdx.x;
    const int bm = blockIdx.x >> 4;
    const int nt = blockIdx.x & 15;
    const int n0 = nt * 8;
    const int w  = t >> 6;

    // Stage weights (512 float4 per matrix, 2 per thread)
    {
        const float4* a4 = (const float4*)W1a;
        const float4* b4 = (const float4*)W1b;
        const float4* c4 = (const float4*)W2a;
        float4* sa = (float4*)sW1a; float4* sb = (float4*)sW1b; float4* sc = (float4*)sW2a;
        sa[t] = a4[t]; sa[t + 256] = a4[t + 256];
        sb[t] = b4[t]; sb[t + 256] = b4[t + 256];
        sc[t] = c4[t]; sc[t + 256] = c4[t + 256];
    }
    if (t < KKC) { sB1a[t] = b1a[t]; sB2a[t] = b2a[t]; }
    if (t < DDC) { sB1b[t] = b1b[t]; }
    if (t < NNC) sAny[t] = 0.f;
    __syncthreads();

    // ---- per-(b,m) stats (redundant per block) ----
    const float4* xs4 = (const float4*)(x + (size_t)bm * ND);
    float4 v4[4];
    float lsum = 0.f;
    #pragma unroll
    for (int s = 0; s < 4; ++s) {
        int f = t + s * 256;
        float4 q = xs4[f];
        v4[s] = q;
        lsum += q.x + q.y + q.z + q.w;
        if (q.x != 0.f || q.y != 0.f || q.z != 0.f || q.w != 0.f) sAny[f >> 3] = 1.f;
    }
    #pragma unroll
    for (int off = 32; off; off >>= 1) lsum += __shfl_xor(lsum, off);
    if ((t & 63) == 0) sRed[w] = lsum;
    __syncthreads();
    const float xsz   = x_size[bm >> 3];
    const float denom = xsz * (float)DDC;
    const int   iN    = (int)(xsz + 0.5f);
    const float mean  = (sRed[0] + sRed[1] + sRed[2] + sRed[3]) / denom;

    float lsq = 0.f;
    #pragma unroll
    for (int s = 0; s < 4; ++s) {
        int f = t + s * 256;
        float mk = sAny[f >> 3];
        float dx = v4[s].x - mean, dy = v4[s].y - mean;
        float dz = v4[s].z - mean, dw = v4[s].w - mean;
        lsq += mk * (dx * dx + dy * dy + dz * dz + dw * dw);
    }
    #pragma unroll
    for (int off = 32; off; off >>= 1) lsq += __shfl_xor(lsq, off);
    __syncthreads();
    if ((t & 63) == 0) sRed[w] = lsq;
    __syncthreads();
    const float sq  = sRed[0] + sRed[1] + sRed[2] + sRed[3];
    const float inv = 1.f / (sqrtf(sq / denom) + SMALLV);

    // ---- normalize own 8-row tile + out pre-init (residual + b3) ----
    {
        float xv = x[(size_t)bm * ND + n0 * DDC + t];
        int  jr  = n0 + (t >> 5);
        sXn[t] = (xv - mean) * inv * sAny[jr];
        out[(size_t)bm * ND + n0 * DDC + t] = (jr < iN) ? xv + b3[0] : 0.f;
    }
    __syncthreads();

    const int k = t & 63;

    // H = gelu(xn @ W1a + b1a): rows w, w+4
    #pragma unroll
    for (int r = 0; r < 2; ++r) {
        int n = w + r * 4;
        const float* xr = &sXn[n * DDC];
        float acc = sB1a[k];
        #pragma unroll
        for (int d = 0; d < DDC; ++d) acc = fmaf(xr[d], sW1a[d * KKC + k], acc);
        sH[n * KKC + k] = gelu_f(acc);
    }
    __syncthreads();

    // x1 = (H @ W1b + b1b) * mask
    {
        const int d2 = t & 31;
        const int n  = t >> 5;
        const float* hr = &sH[n * KKC];
        float acc = sB1b[d2];
        #pragma unroll
        for (int q = 0; q < KKC; ++q) acc = fmaf(hr[q], sW1b[q * DDC + d2], acc);
        float val = acc * sAny[n0 + n];
        sX1[n * DDC + d2] = val;
        x1g[(size_t)bm * ND + (n0 + n) * DDC + d2] = val;
    }
    __syncthreads();

    // A1 = x1@W2a + b2a ; A2 = xn@W2a (transposed store [k][j])
    #pragma unroll
    for (int r = 0; r < 2; ++r) {
        int n = w + r * 4;
        const float* x1r = &sX1[n * DDC];
        const float* xnr = &sXn[n * DDC];
        float a1 = sB2a[k], a2 = 0.f;
        #pragma unroll
        for (int d = 0; d < DDC; ++d) {
            a1 = fmaf(x1r[d], sW2a[d * KKC + k], a1);
            a2 = fmaf(xnr[d], sW2a[d * KKC + k], a2);
        }
        A1g[(size_t)bm * NK + (n0 + n) * KKC + k] = a1;
        A2t[(size_t)bm * NK + k * NNC + (n0 + n)] = a2;
    }

    if (blockIdx.x == 0) {
        // v2[k] = sum_h W2b[k][h]*w3[h]
        int kk = t >> 2, hq = t & 3;
        float p = 0.f;
        #pragma unroll
        for (int h = 0; h < 16; ++h)
            p = fmaf(W2b[kk * KKC + hq * 16 + h], w3[hq * 16 + h], p);
        __syncthreads();
        sH[t] = p;
        __syncthreads();
        if (hq == 0) v2g[kk] = sH[t] + sH[t + 1] + sH[t + 2] + sH[t + 3];
        if (t < 64) {
            float q = b2b[t] * w3[t];
            #pragma unroll
            for (int off = 32; off; off >>= 1) q += __shfl_xor(q, off);
            if (t == 0) c3g[0] = q;
        }
    }
}

// ---------------------------------------------------------------------------
// Kernel 2: pair interactions + atomic finish. Grid = bm(32) x jg(2) x ig(8)
// = 512 blocks x 256. Block = 16 i x 64 j. Phase 1: wave = 4 i-chains,
// lane = j; a2[64] in VGPRs; A1/v2 via broadcast ds_read_b128. Phase 2:
// rank-1 update, atomicAdd into out for valid j.
// ---------------------------------------------------------------------------
__global__ __launch_bounds__(256) void pair_kernel(
    const float* __restrict__ x_size,
    const float* __restrict__ A1g, const float* __restrict__ A2t,
    const float* __restrict__ x1g, const float* __restrict__ v2g,
    const float* __restrict__ c3g, float* __restrict__ out)
{
    __shared__ float sA2[KKC * 64];   // [k][j] 16 KB
    __shared__ float sA1[16 * KKC];   // 4 KB
    __shared__ float sX1[16 * DDC];   // 2 KB
    __shared__ float sS[16 * 64];     // 4 KB
    __shared__ float sV2[KKC];

    const int t    = threadIdx.x;
    const int bm   = blockIdx.x >> 4;
    const int jg   = (blockIdx.x >> 3) & 1;
    const int ig   = blockIdx.x & 7;

    const int iN = (int)(x_size[bm >> 3] + 0.5f);
    if (ig * 16 >= iN || jg * 64 >= iN) return;   // fully-padded tile

    const int wv   = t >> 6;
    const int lane = t & 63;

    // ---- stage A2 tile [k][j-local] ----
    {
        const float* A2b = A2t + (size_t)bm * NK + jg * 64;
        float4* s4 = (float4*)sA2;
        #pragma unroll
        for (int s = 0; s < 4; ++s) {
            int idx = t + s * 256;          // float4 index
            int k = idx >> 4, f = idx & 15;
            s4[idx] = *(const float4*)(A2b + k * NNC + f * 4);
        }
    }
    // A1: 16 rows x 64 = 1024 floats; x1: 16 x 32 = 512 floats; v2
    ((float4*)sA1)[t] = ((const float4*)(A1g + (size_t)bm * NK + ig * 16 * KKC))[t];
    ((float2*)sX1)[t] = ((const float2*)(x1g + (size_t)bm * ND + ig * 16 * DDC))[t];
    if (t < KKC) sV2[t] = v2g[t];
    const float c3 = c3g[0];
    __syncthreads();

    // a2 column for this lane's j -> 64 VGPRs (stride-64 = 2-way, free)
    float a2r[KKC];
    #pragma unroll
    for (int q = 0; q < KKC; ++q) a2r[q] = sA2[q * 64 + lane];

    // ---- phase 1: wave wv = i-chains 4*wv .. 4*wv+3 ----
    {
        const float4* a1f0 = (const float4*)&sA1[(wv * 4 + 0) * KKC];
        const float4* a1f1 = (const float4*)&sA1[(wv * 4 + 1) * KKC];
        const float4* a1f2 = (const float4*)&sA1[(wv * 4 + 2) * KKC];
        const float4* a1f3 = (const float4*)&sA1[(wv * 4 + 3) * KKC];
        const float4* v2f  = (const float4*)sV2;
        float S0 = c3, S1 = c3, S2 = c3, S3 = c3;
        #pragma unroll 4
        for (int k4 = 0; k4 < 16; ++k4) {
            float4 vk = v2f[k4];
            float4 a0 = a1f0[k4];
            float4 a1 = a1f1[k4];
            float4 a2 = a1f2[k4];
            float4 a3 = a1f3[k4];
            const int kb = k4 * 4;
            float b0 = a2r[kb + 0], b1 = a2r[kb + 1], b2 = a2r[kb + 2], b3v = a2r[kb + 3];
            S0 = fmaf(gelu_f(a0.x - b0), vk.x, S0);
            S1 = fmaf(gelu_f(a1.x - b0), vk.x, S1);
            S2 = fmaf(gelu_f(a2.x - b0), vk.x, S2);
            S3 = fmaf(gelu_f(a3.x - b0), vk.x, S3);
            S0 = fmaf(gelu_f(a0.y - b1), vk.y, S0);
            S1 = fmaf(gelu_f(a1.y - b1), vk.y, S1);
            S2 = fmaf(gelu_f(a2.y - b1), vk.y, S2);
            S3 = fmaf(gelu_f(a3.y - b1), vk.y, S3);
            S0 = fmaf(gelu_f(a0.z - b2), vk.z, S0);
            S1 = fmaf(gelu_f(a1.z - b2), vk.z, S1);
            S2 = fmaf(gelu_f(a2.z - b2), vk.z, S2);
            S3 = fmaf(gelu_f(a3.z - b2), vk.z, S3);
            S0 = fmaf(gelu_f(a0.w - b3v), vk.w, S0);
            S1 = fmaf(gelu_f(a1.w - b3v), vk.w, S1);
            S2 = fmaf(gelu_f(a2.w - b3v), vk.w, S2);
            S3 = fmaf(gelu_f(a3.w - b3v), vk.w, S3);
        }
        sS[(wv * 4 + 0) * 64 + lane] = S0;
        sS[(wv * 4 + 1) * 64 + lane] = S1;
        sS[(wv * 4 + 2) * 64 + lane] = S2;
        sS[(wv * 4 + 3) * 64 + lane] = S3;
    }
    __syncthreads();

    // ---- phase 2: thread = (j = t>>2, dq = t&3); 16 i; atomic finish ----
    {
        const int j  = t >> 2;
        const int dq = t & 3;
        float acc[8];
        #pragma unroll
        for (int d = 0; d < 8; ++d) acc[d] = 0.f;
        #pragma unroll
        for (int i = 0; i < 16; ++i) {
            float Sv = sS[i * 64 + j];
            const float4* xf = (const float4*)&sX1[i * DDC + dq * 8];
            float4 xa = xf[0], xb = xf[1];
            acc[0] = fmaf(Sv, xa.x, acc[0]);
            acc[1] = fmaf(Sv, xa.y, acc[1]);
            acc[2] = fmaf(Sv, xa.z, acc[2]);
            acc[3] = fmaf(Sv, xa.w, acc[3]);
            acc[4] = fmaf(Sv, xb.x, acc[4]);
            acc[5] = fmaf(Sv, xb.y, acc[5]);
            acc[6] = fmaf(Sv, xb.z, acc[6]);
            acc[7] = fmaf(Sv, xb.w, acc[7]);
        }
        const int jglob = jg * 64 + j;
        if (jglob < iN) {
            float* ob = out + (size_t)bm * ND + jglob * DDC + dq * 8;
            #pragma unroll
            for (int q = 0; q < 8; ++q) atomicAdd(ob + q, acc[q]);
        }
    }
}

extern "C" void kernel_launch(void* const* d_in, const int* in_sizes, int n_in,
                              void* d_out, int out_size, void* d_ws, size_t ws_size,
                              hipStream_t stream) {
    const float* x      = (const float*)d_in[0];
    const float* x_size = (const float*)d_in[1];
    const float* W1a    = (const float*)d_in[2];
    const float* b1a    = (const float*)d_in[3];
    const float* W1b    = (const float*)d_in[4];
    const float* b1b    = (const float*)d_in[5];
    const float* W2a    = (const float*)d_in[6];
    const float* b2a    = (const float*)d_in[7];
    const float* W2b    = (const float*)d_in[8];
    const float* b2b    = (const float*)d_in[9];
    const float* w3     = (const float*)d_in[10];
    const float* b3     = (const float*)d_in[11];
    float* out = (float*)d_out;

    float* ws  = (float*)d_ws;
    float* x1g = ws;                       // 131072
    float* A1g = x1g + (size_t)BMC * ND;   // 262144
    float* A2t = A1g + (size_t)BMC * NK;   // 262144
    float* v2g = A2t + (size_t)BMC * NK;   // 64
    float* c3g = v2g + KKC;                // 1 (+63 pad)

    mlp_kernel<<<BMC * 16, 256, 0, stream>>>(x, x_size,
        W1a, b1a, W1b, b1b, W2a, b2a, W2b, b2b, w3, b3,
        x1g, A1g, A2t, v2g, c3g, out);
    pair_kernel<<<BMC * 16, 256, 0, stream>>>(x_size, A1g, A2t, x1g, v2g, c3g, out);
}

// Round 7
// 113.125 us; speedup vs baseline: 1.0844x; 1.0844x over previous
//
#include <hip/hip_runtime.h>

// B=4, M=8, N=128, D=32, K=2D=H=64
#define BMC 32
#define NNC 128
#define DDC 32
#define KKC 64
constexpr int ND = NNC * DDC;   // 4096
constexpr int NK = NNC * KKC;   // 8192
constexpr int NS = NNC * NNC;   // 16384 (S matrix per bm)
#define SMALLV 1e-8f

__device__ __forceinline__ float gelu_f(float v) {
    // tanh-gelu folded: gelu(v) = v - v * rcp(1 + exp2(v*(a*v^2+b)))
    float v2 = v * v;
    float p  = fmaf(0.1029432f, v2, 2.3022082f);
    float e  = __builtin_amdgcn_exp2f(v * p);
    float r  = __builtin_amdgcn_rcpf(e + 1.0f);
    return fmaf(-v, r, v);
}

// ---------------------------------------------------------------------------
// Kernel 1: fused stats + MLP1 + A1/A2. Grid = bm(32) x nt(16) = 512 x 256.
// A2 stored row-major [j][k] so score_kernel lanes can bulk-load their row.
// ---------------------------------------------------------------------------
__global__ __launch_bounds__(256) void mlp_kernel(
    const float* __restrict__ x, const float* __restrict__ x_size,
    const float* __restrict__ W1a, const float* __restrict__ b1a,
    const float* __restrict__ W1b, const float* __restrict__ b1b,
    const float* __restrict__ W2a, const float* __restrict__ b2a,
    const float* __restrict__ W2b, const float* __restrict__ b2b,
    const float* __restrict__ w3,
    float* __restrict__ x1g, float* __restrict__ A1g, float* __restrict__ A2r,
    float* __restrict__ v2g, float* __restrict__ c3g)
{
    __shared__ float sW1a[DDC * KKC];   // 8 KB
    __shared__ float sW1b[KKC * DDC];   // 8 KB
    __shared__ float sW2a[DDC * KKC];   // 8 KB
    __shared__ float sXn[8 * DDC];
    __shared__ float sH[8 * KKC];
    __shared__ float sX1[8 * DDC];
    __shared__ float sB1a[KKC], sB2a[KKC], sB1b[DDC];
    __shared__ float sAny[NNC];
    __shared__ float sRed[4];

    const int t  = threadIdx.x;
    const int bm = blockIdx.x >> 4;
    const int nt = blockIdx.x & 15;
    const int n0 = nt * 8;
    const int w  = t >> 6;

    // Stage weights (512 float4 per matrix, 2 per thread)
    {
        const float4* a4 = (const float4*)W1a;
        const float4* b4 = (const float4*)W1b;
        const float4* c4 = (const float4*)W2a;
        float4* sa = (float4*)sW1a; float4* sb = (float4*)sW1b; float4* sc = (float4*)sW2a;
        sa[t] = a4[t]; sa[t + 256] = a4[t + 256];
        sb[t] = b4[t]; sb[t + 256] = b4[t + 256];
        sc[t] = c4[t]; sc[t + 256] = c4[t + 256];
    }
    if (t < KKC) { sB1a[t] = b1a[t]; sB2a[t] = b2a[t]; }
    if (t < DDC) { sB1b[t] = b1b[t]; }
    if (t < NNC) sAny[t] = 0.f;
    __syncthreads();

    // ---- per-(b,m) stats (redundant per block) ----
    const float4* xs4 = (const float4*)(x + (size_t)bm * ND);
    float4 v4[4];
    float lsum = 0.f;
    #pragma unroll
    for (int s = 0; s < 4; ++s) {
        int f = t + s * 256;
        float4 q = xs4[f];
        v4[s] = q;
        lsum += q.x + q.y + q.z + q.w;
        if (q.x != 0.f || q.y != 0.f || q.z != 0.f || q.w != 0.f) sAny[f >> 3] = 1.f;
    }
    #pragma unroll
    for (int off = 32; off; off >>= 1) lsum += __shfl_xor(lsum, off);
    if ((t & 63) == 0) sRed[w] = lsum;
    __syncthreads();
    const float xsz   = x_size[bm >> 3];
    const float denom = xsz * (float)DDC;
    const float mean  = (sRed[0] + sRed[1] + sRed[2] + sRed[3]) / denom;

    float lsq = 0.f;
    #pragma unroll
    for (int s = 0; s < 4; ++s) {
        int f = t + s * 256;
        float mk = sAny[f >> 3];
        float dx = v4[s].x - mean, dy = v4[s].y - mean;
        float dz = v4[s].z - mean, dw = v4[s].w - mean;
        lsq += mk * (dx * dx + dy * dy + dz * dz + dw * dw);
    }
    #pragma unroll
    for (int off = 32; off; off >>= 1) lsq += __shfl_xor(lsq, off);
    __syncthreads();
    if ((t & 63) == 0) sRed[w] = lsq;
    __syncthreads();
    const float sq  = sRed[0] + sRed[1] + sRed[2] + sRed[3];
    const float inv = 1.f / (sqrtf(sq / denom) + SMALLV);

    // ---- normalize own 8-row tile ----
    {
        float xv = x[(size_t)bm * ND + n0 * DDC + t];
        sXn[t] = (xv - mean) * inv * sAny[n0 + (t >> 5)];
    }
    __syncthreads();

    const int k = t & 63;

    // H = gelu(xn @ W1a + b1a): rows w, w+4
    #pragma unroll
    for (int r = 0; r < 2; ++r) {
        int n = w + r * 4;
        const float* xr = &sXn[n * DDC];
        float acc = sB1a[k];
        #pragma unroll
        for (int d = 0; d < DDC; ++d) acc = fmaf(xr[d], sW1a[d * KKC + k], acc);
        sH[n * KKC + k] = gelu_f(acc);
    }
    __syncthreads();

    // x1 = (H @ W1b + b1b) * mask
    {
        const int d2 = t & 31;
        const int n  = t >> 5;
        const float* hr = &sH[n * KKC];
        float acc = sB1b[d2];
        #pragma unroll
        for (int q = 0; q < KKC; ++q) acc = fmaf(hr[q], sW1b[q * DDC + d2], acc);
        float val = acc * sAny[n0 + n];
        sX1[n * DDC + d2] = val;
        x1g[(size_t)bm * ND + (n0 + n) * DDC + d2] = val;
    }
    __syncthreads();

    // A1 = x1@W2a + b2a ; A2 = xn@W2a (both row-major [n][k])
    #pragma unroll
    for (int r = 0; r < 2; ++r) {
        int n = w + r * 4;
        const float* x1r = &sX1[n * DDC];
        const float* xnr = &sXn[n * DDC];
        float a1 = sB2a[k], a2 = 0.f;
        #pragma unroll
        for (int d = 0; d < DDC; ++d) {
            a1 = fmaf(x1r[d], sW2a[d * KKC + k], a1);
            a2 = fmaf(xnr[d], sW2a[d * KKC + k], a2);
        }
        A1g[(size_t)bm * NK + (n0 + n) * KKC + k] = a1;
        A2r[(size_t)bm * NK + (n0 + n) * KKC + k] = a2;
    }

    if (blockIdx.x == 0) {
        // v2[k] = sum_h W2b[k][h]*w3[h]
        int kk = t >> 2, hq = t & 3;
        float p = 0.f;
        #pragma unroll
        for (int h = 0; h < 16; ++h)
            p = fmaf(W2b[kk * KKC + hq * 16 + h], w3[hq * 16 + h], p);
        __syncthreads();
        sH[t] = p;
        __syncthreads();
        if (hq == 0) v2g[kk] = sH[t] + sH[t + 1] + sH[t + 2] + sH[t + 3];
        if (t < 64) {
            float q = b2b[t] * w3[t];
            #pragma unroll
            for (int off = 32; off; off >>= 1) q += __shfl_xor(q, off);
            if (t == 0) c3g[0] = q;
        }
    }
}

// ---------------------------------------------------------------------------
// Kernel 2: score S[i,j] = sum_k gelu(A1[i,k]-A2[j,k])*v2[k] + c3.
// Grid = bm(32) x jg(2) x ig(16) = 1024 blocks x 256 (4 waves, 2 i-chains
// each). lane = j-local. a2 row in 16 float4 VGPRs (global bulk load);
// A1 tile + v2 in tiny LDS (2.3 KB -> high blocks/CU). Fully unrolled k.
// ---------------------------------------------------------------------------
__global__ __launch_bounds__(256, 4) void score_kernel(
    const float* __restrict__ x_size,
    const float* __restrict__ A1g, const float* __restrict__ A2r,
    const float* __restrict__ v2g, const float* __restrict__ c3g,
    float* __restrict__ Sg)
{
    __shared__ float sA1[8 * KKC];   // 2 KB
    __shared__ float sV2[KKC];

    const int t  = threadIdx.x;
    const int bm = blockIdx.x >> 5;
    const int jg = (blockIdx.x >> 4) & 1;
    const int ig = blockIdx.x & 15;

    const int iN = (int)(x_size[bm >> 3] + 0.5f);
    if (ig * 8 >= iN || jg * 64 >= iN) return;   // fully-padded tile

    const int wv   = t >> 6;
    const int lane = t & 63;

    // stage A1 tile (8 rows x 64) + v2
    ((float2*)sA1)[t] = ((const float2*)(A1g + (size_t)bm * NK + ig * 8 * KKC))[t];
    if (t < KKC) sV2[t] = v2g[t];
    const float c3 = c3g[0];

    // a2 row for this lane's j: 16 float4 registers from global (L2-resident)
    const float4* a2p = (const float4*)(A2r + (size_t)bm * NK + (jg * 64 + lane) * KKC);
    float4 a2q[16];
    #pragma unroll
    for (int q = 0; q < 16; ++q) a2q[q] = a2p[q];
    __syncthreads();

    const float4* a1f0 = (const float4*)&sA1[(wv * 2 + 0) * KKC];
    const float4* a1f1 = (const float4*)&sA1[(wv * 2 + 1) * KKC];
    const float4* v2f  = (const float4*)sV2;

    float S0 = c3, S1 = c3;
    #pragma unroll
    for (int q = 0; q < 16; ++q) {
        float4 a0 = a1f0[q];
        float4 a1 = a1f1[q];
        float4 vv = v2f[q];
        float4 b  = a2q[q];
        S0 = fmaf(gelu_f(a0.x - b.x), vv.x, S0);
        S1 = fmaf(gelu_f(a1.x - b.x), vv.x, S1);
        S0 = fmaf(gelu_f(a0.y - b.y), vv.y, S0);
        S1 = fmaf(gelu_f(a1.y - b.y), vv.y, S1);
        S0 = fmaf(gelu_f(a0.z - b.z), vv.z, S0);
        S1 = fmaf(gelu_f(a1.z - b.z), vv.z, S1);
        S0 = fmaf(gelu_f(a0.w - b.w), vv.w, S0);
        S1 = fmaf(gelu_f(a1.w - b.w), vv.w, S1);
    }
    const int i0 = ig * 8 + wv * 2;
    const int jc = jg * 64 + lane;
    Sg[(size_t)bm * NS + (i0 + 0) * NNC + jc] = S0;
    Sg[(size_t)bm * NS + (i0 + 1) * NNC + jc] = S1;
}

// ---------------------------------------------------------------------------
// Kernel 3: out[bm,j,d] = sum_{i<iN} S[i,j]*x1[i,d] + b3 + x, masked.
// One thread per output element; S reads are wave-broadcast lines, x1
// coalesced. 512 blocks x 256.
// ---------------------------------------------------------------------------
__global__ __launch_bounds__(256) void agg_kernel(
    const float* __restrict__ x, const float* __restrict__ x_size,
    const float* __restrict__ b3,
    const float* __restrict__ Sg, const float* __restrict__ x1g,
    float* __restrict__ out)
{
    const int gid = blockIdx.x * 256 + threadIdx.x;   // < 131072
    const int bm  = gid >> 12;
    const int d   = gid & 31;
    const int j   = (gid >> 5) & 127;
    const int iN  = (int)(x_size[bm >> 3] + 0.5f);
    if (j >= iN) { out[gid] = 0.f; return; }

    const float* Sp = Sg + (size_t)bm * NS + j;
    const float* xp = x1g + (size_t)bm * ND + d;
    float a0 = 0.f, a1 = 0.f, a2 = 0.f, a3 = 0.f;
    int i = 0;
    for (; i + 4 <= iN; i += 4) {
        a0 = fmaf(Sp[(i + 0) * NNC], xp[(i + 0) * DDC], a0);
        a1 = fmaf(Sp[(i + 1) * NNC], xp[(i + 1) * DDC], a1);
        a2 = fmaf(Sp[(i + 2) * NNC], xp[(i + 2) * DDC], a2);
        a3 = fmaf(Sp[(i + 3) * NNC], xp[(i + 3) * DDC], a3);
    }
    for (; i < iN; ++i) a0 = fmaf(Sp[i * NNC], xp[i * DDC], a0);
    out[gid] = (a0 + a1) + (a2 + a3) + b3[0] + x[gid];
}

extern "C" void kernel_launch(void* const* d_in, const int* in_sizes, int n_in,
                              void* d_out, int out_size, void* d_ws, size_t ws_size,
                              hipStream_t stream) {
    const float* x      = (const float*)d_in[0];
    const float* x_size = (const float*)d_in[1];
    const float* W1a    = (const float*)d_in[2];
    const float* b1a    = (const float*)d_in[3];
    const float* W1b    = (const float*)d_in[4];
    const float* b1b    = (const float*)d_in[5];
    const float* W2a    = (const float*)d_in[6];
    const float* b2a    = (const float*)d_in[7];
    const float* W2b    = (const float*)d_in[8];
    const float* b2b    = (const float*)d_in[9];
    const float* w3     = (const float*)d_in[10];
    const float* b3     = (const float*)d_in[11];
    float* out = (float*)d_out;

    float* ws  = (float*)d_ws;
    float* x1g = ws;                       // 131072
    float* A1g = x1g + (size_t)BMC * ND;   // 262144
    float* A2r = A1g + (size_t)BMC * NK;   // 262144
    float* v2g = A2r + (size_t)BMC * NK;   // 64
    float* c3g = v2g + KKC;                // 1 (+63 pad)
    float* Sg  = c3g + 64;                 // 32*16384 = 524288 (2 MB)

    mlp_kernel<<<BMC * 16, 256, 0, stream>>>(x, x_size,
        W1a, b1a, W1b, b1b, W2a, b2a, W2b, b2b, w3,
        x1g, A1g, A2r, v2g, c3g);
    score_kernel<<<BMC * 32, 256, 0, stream>>>(x_size, A1g, A2r, v2g, c3g, Sg);
    agg_kernel<<<512, 256, 0, stream>>>(x, x_size, b3, Sg, x1g, out);
}

// Round 8
// 104.715 us; speedup vs baseline: 1.1715x; 1.0803x over previous
//
#include <hip/hip_runtime.h>

// B=4, M=8, N=128, D=32, K=2D=H=64
#define BMC 32
#define NNC 128
#define DDC 32
#define KKC 64
constexpr int ND = NNC * DDC;   // 4096
constexpr int NK = NNC * KKC;   // 8192
#define SMALLV 1e-8f

__device__ __forceinline__ float gelu_f(float v) {
    // tanh-gelu folded: gelu(v) = v - v * rcp(1 + exp2(v*(a*v^2+b)))
    float v2 = v * v;
    float p  = fmaf(0.1029432f, v2, 2.3022082f);
    float e  = __builtin_amdgcn_exp2f(v * p);
    float r  = __builtin_amdgcn_rcpf(e + 1.0f);
    return fmaf(-v, r, v);
}

// ---------------------------------------------------------------------------
// Kernel 1: fused stats + MLP1 + A1/A2. Grid = bm(32) x nt(16) = 512 x 256.
// A1 and A2 both stored row-major [n][k]; A2 rows feed pair's VGPR bulk load.
// ---------------------------------------------------------------------------
__global__ __launch_bounds__(256) void mlp_kernel(
    const float* __restrict__ x, const float* __restrict__ x_size,
    const float* __restrict__ W1a, const float* __restrict__ b1a,
    const float* __restrict__ W1b, const float* __restrict__ b1b,
    const float* __restrict__ W2a, const float* __restrict__ b2a,
    const float* __restrict__ W2b, const float* __restrict__ b2b,
    const float* __restrict__ w3,
    float* __restrict__ x1g, float* __restrict__ A1g, float* __restrict__ A2r,
    float* __restrict__ v2g, float* __restrict__ c3g)
{
    __shared__ float sW1a[DDC * KKC];   // 8 KB
    __shared__ float sW1b[KKC * DDC];   // 8 KB
    __shared__ float sW2a[DDC * KKC];   // 8 KB
    __shared__ float sXn[8 * DDC];
    __shared__ float sH[8 * KKC];
    __shared__ float sX1[8 * DDC];
    __shared__ float sB1a[KKC], sB2a[KKC], sB1b[DDC];
    __shared__ float sAny[NNC];
    __shared__ float sRed[4];

    const int t  = threadIdx.x;
    const int bm = blockIdx.x >> 4;
    const int nt = blockIdx.x & 15;
    const int n0 = nt * 8;
    const int w  = t >> 6;

    // Stage weights (512 float4 per matrix, 2 per thread)
    {
        const float4* a4 = (const float4*)W1a;
        const float4* b4 = (const float4*)W1b;
        const float4* c4 = (const float4*)W2a;
        float4* sa = (float4*)sW1a; float4* sb = (float4*)sW1b; float4* sc = (float4*)sW2a;
        sa[t] = a4[t]; sa[t + 256] = a4[t + 256];
        sb[t] = b4[t]; sb[t + 256] = b4[t + 256];
        sc[t] = c4[t]; sc[t + 256] = c4[t + 256];
    }
    if (t < KKC) { sB1a[t] = b1a[t]; sB2a[t] = b2a[t]; }
    if (t < DDC) { sB1b[t] = b1b[t]; }
    if (t < NNC) sAny[t] = 0.f;
    __syncthreads();

    // ---- per-(b,m) stats (redundant per block) ----
    const float4* xs4 = (const float4*)(x + (size_t)bm * ND);
    float4 v4[4];
    float lsum = 0.f;
    #pragma unroll
    for (int s = 0; s < 4; ++s) {
        int f = t + s * 256;
        float4 q = xs4[f];
        v4[s] = q;
        lsum += q.x + q.y + q.z + q.w;
        if (q.x != 0.f || q.y != 0.f || q.z != 0.f || q.w != 0.f) sAny[f >> 3] = 1.f;
    }
    #pragma unroll
    for (int off = 32; off; off >>= 1) lsum += __shfl_xor(lsum, off);
    if ((t & 63) == 0) sRed[w] = lsum;
    __syncthreads();
    const float xsz   = x_size[bm >> 3];
    const float denom = xsz * (float)DDC;
    const float mean  = (sRed[0] + sRed[1] + sRed[2] + sRed[3]) / denom;

    float lsq = 0.f;
    #pragma unroll
    for (int s = 0; s < 4; ++s) {
        int f = t + s * 256;
        float mk = sAny[f >> 3];
        float dx = v4[s].x - mean, dy = v4[s].y - mean;
        float dz = v4[s].z - mean, dw = v4[s].w - mean;
        lsq += mk * (dx * dx + dy * dy + dz * dz + dw * dw);
    }
    #pragma unroll
    for (int off = 32; off; off >>= 1) lsq += __shfl_xor(lsq, off);
    __syncthreads();
    if ((t & 63) == 0) sRed[w] = lsq;
    __syncthreads();
    const float sq  = sRed[0] + sRed[1] + sRed[2] + sRed[3];
    const float inv = 1.f / (sqrtf(sq / denom) + SMALLV);

    // ---- normalize own 8-row tile ----
    {
        float xv = x[(size_t)bm * ND + n0 * DDC + t];
        sXn[t] = (xv - mean) * inv * sAny[n0 + (t >> 5)];
    }
    __syncthreads();

    const int k = t & 63;

    // H = gelu(xn @ W1a + b1a): rows w, w+4
    #pragma unroll
    for (int r = 0; r < 2; ++r) {
        int n = w + r * 4;
        const float* xr = &sXn[n * DDC];
        float acc = sB1a[k];
        #pragma unroll
        for (int d = 0; d < DDC; ++d) acc = fmaf(xr[d], sW1a[d * KKC + k], acc);
        sH[n * KKC + k] = gelu_f(acc);
    }
    __syncthreads();

    // x1 = (H @ W1b + b1b) * mask
    {
        const int d2 = t & 31;
        const int n  = t >> 5;
        const float* hr = &sH[n * KKC];
        float acc = sB1b[d2];
        #pragma unroll
        for (int q = 0; q < KKC; ++q) acc = fmaf(hr[q], sW1b[q * DDC + d2], acc);
        float val = acc * sAny[n0 + n];
        sX1[n * DDC + d2] = val;
        x1g[(size_t)bm * ND + (n0 + n) * DDC + d2] = val;
    }
    __syncthreads();

    // A1 = x1@W2a + b2a ; A2 = xn@W2a (both row-major [n][k])
    #pragma unroll
    for (int r = 0; r < 2; ++r) {
        int n = w + r * 4;
        const float* x1r = &sX1[n * DDC];
        const float* xnr = &sXn[n * DDC];
        float a1 = sB2a[k], a2 = 0.f;
        #pragma unroll
        for (int d = 0; d < DDC; ++d) {
            a1 = fmaf(x1r[d], sW2a[d * KKC + k], a1);
            a2 = fmaf(xnr[d], sW2a[d * KKC + k], a2);
        }
        A1g[(size_t)bm * NK + (n0 + n) * KKC + k] = a1;
        A2r[(size_t)bm * NK + (n0 + n) * KKC + k] = a2;
    }

    if (blockIdx.x == 0) {
        // v2[k] = sum_h W2b[k][h]*w3[h]
        int kk = t >> 2, hq = t & 3;
        float p = 0.f;
        #pragma unroll
        for (int h = 0; h < 16; ++h)
            p = fmaf(W2b[kk * KKC + hq * 16 + h], w3[hq * 16 + h], p);
        __syncthreads();
        sH[t] = p;
        __syncthreads();
        if (hq == 0) v2g[kk] = sH[t] + sH[t + 1] + sH[t + 2] + sH[t + 3];
        if (t < 64) {
            float q = b2b[t] * w3[t];
            #pragma unroll
            for (int off = 32; off; off >>= 1) q += __shfl_xor(q, off);
            if (t == 0) c3g[0] = q;
        }
    }
}

// ---------------------------------------------------------------------------
// Kernel 2: pair. Grid = bm(32) x jg(2) x ig(8) = 512 blocks x 256.
// Block = 16 i x 64 j. Phase 1: wave = 4 i-chains, lane = j; a2 row in 16
// float4 VGPRs (bulk global load from [j][k] layout); A1 tile + v2 in tiny
// LDS. Phase 2: rank-1 update from LDS S, write 4 MB partial (no atomics).
// ---------------------------------------------------------------------------
__global__ __launch_bounds__(256, 4) void pair_kernel(
    const float* __restrict__ x_size,
    const float* __restrict__ A1g, const float* __restrict__ A2r,
    const float* __restrict__ x1g, const float* __restrict__ v2g,
    const float* __restrict__ c3g, float* __restrict__ partial)
{
    __shared__ float sA1[16 * KKC];   // 4 KB
    __shared__ float sX1[16 * DDC];   // 2 KB
    __shared__ float sS[16 * 64];     // 4 KB
    __shared__ float sV2[KKC];

    const int t  = threadIdx.x;
    const int bm = blockIdx.x >> 4;
    const int jg = (blockIdx.x >> 3) & 1;
    const int ig = blockIdx.x & 7;

    const int iN = (int)(x_size[bm >> 3] + 0.5f);
    if (ig * 16 >= iN || jg * 64 >= iN) return;   // fully-padded tile

    const int wv   = t >> 6;
    const int lane = t & 63;

    // stage A1 tile (16 x 64) + x1 tile (16 x 32) + v2
    ((float4*)sA1)[t] = ((const float4*)(A1g + (size_t)bm * NK + ig * 16 * KKC))[t];
    ((float2*)sX1)[t] = ((const float2*)(x1g + (size_t)bm * ND + ig * 16 * DDC))[t];
    if (t < KKC) sV2[t] = v2g[t];
    const float c3 = c3g[0];

    // a2 row for this lane's j: 16 float4 registers (L2-resident)
    const float4* a2p = (const float4*)(A2r + (size_t)bm * NK + (jg * 64 + lane) * KKC);
    float4 a2q[16];
    #pragma unroll
    for (int q = 0; q < 16; ++q) a2q[q] = a2p[q];
    __syncthreads();

    // ---- phase 1: wave wv = 4 i-chains ----
    {
        const float4* a1f0 = (const float4*)&sA1[(wv * 4 + 0) * KKC];
        const float4* a1f1 = (const float4*)&sA1[(wv * 4 + 1) * KKC];
        const float4* a1f2 = (const float4*)&sA1[(wv * 4 + 2) * KKC];
        const float4* a1f3 = (const float4*)&sA1[(wv * 4 + 3) * KKC];
        const float4* v2f  = (const float4*)sV2;
        float S0 = c3, S1 = c3, S2 = c3, S3 = c3;
        #pragma unroll
        for (int q = 0; q < 16; ++q) {
            float4 vv = v2f[q];
            float4 a0 = a1f0[q];
            float4 a1 = a1f1[q];
            float4 a2 = a1f2[q];
            float4 a3 = a1f3[q];
            float4 b  = a2q[q];
            S0 = fmaf(gelu_f(a0.x - b.x), vv.x, S0);
            S1 = fmaf(gelu_f(a1.x - b.x), vv.x, S1);
            S2 = fmaf(gelu_f(a2.x - b.x), vv.x, S2);
            S3 = fmaf(gelu_f(a3.x - b.x), vv.x, S3);
            S0 = fmaf(gelu_f(a0.y - b.y), vv.y, S0);
            S1 = fmaf(gelu_f(a1.y - b.y), vv.y, S1);
            S2 = fmaf(gelu_f(a2.y - b.y), vv.y, S2);
            S3 = fmaf(gelu_f(a3.y - b.y), vv.y, S3);
            S0 = fmaf(gelu_f(a0.z - b.z), vv.z, S0);
            S1 = fmaf(gelu_f(a1.z - b.z), vv.z, S1);
            S2 = fmaf(gelu_f(a2.z - b.z), vv.z, S2);
            S3 = fmaf(gelu_f(a3.z - b.z), vv.z, S3);
            S0 = fmaf(gelu_f(a0.w - b.w), vv.w, S0);
            S1 = fmaf(gelu_f(a1.w - b.w), vv.w, S1);
            S2 = fmaf(gelu_f(a2.w - b.w), vv.w, S2);
            S3 = fmaf(gelu_f(a3.w - b.w), vv.w, S3);
        }
        sS[(wv * 4 + 0) * 64 + lane] = S0;
        sS[(wv * 4 + 1) * 64 + lane] = S1;
        sS[(wv * 4 + 2) * 64 + lane] = S2;
        sS[(wv * 4 + 3) * 64 + lane] = S3;
    }
    __syncthreads();

    // ---- phase 2: thread = (j = t>>2, dq = t&3); 16 i; write partial ----
    {
        const int j  = t >> 2;
        const int dq = t & 3;
        float acc[8];
        #pragma unroll
        for (int d = 0; d < 8; ++d) acc[d] = 0.f;
        #pragma unroll
        for (int i = 0; i < 16; ++i) {
            float Sv = sS[i * 64 + j];
            const float4* xf = (const float4*)&sX1[i * DDC + dq * 8];
            float4 xa = xf[0], xb = xf[1];
            acc[0] = fmaf(Sv, xa.x, acc[0]);
            acc[1] = fmaf(Sv, xa.y, acc[1]);
            acc[2] = fmaf(Sv, xa.z, acc[2]);
            acc[3] = fmaf(Sv, xa.w, acc[3]);
            acc[4] = fmaf(Sv, xb.x, acc[4]);
            acc[5] = fmaf(Sv, xb.y, acc[5]);
            acc[6] = fmaf(Sv, xb.z, acc[6]);
            acc[7] = fmaf(Sv, xb.w, acc[7]);
        }
        // partial layout: [bm][jg][ig][j][d]; thread-contiguous t*8
        float* pb = partial + (size_t)blockIdx.x * 2048 + t * 8;
        ((float4*)pb)[0] = make_float4(acc[0], acc[1], acc[2], acc[3]);
        ((float4*)pb)[1] = make_float4(acc[4], acc[5], acc[6], acc[7]);
    }
}

// ---------------------------------------------------------------------------
// Kernel 3: sum valid i-group partials, add b3 + residual, mask j >= iN.
// ---------------------------------------------------------------------------
__global__ __launch_bounds__(256) void final_kernel(
    const float* __restrict__ x, const float* __restrict__ x_size,
    const float* __restrict__ b3,
    const float* __restrict__ partial, float* __restrict__ out)
{
    const int gid = blockIdx.x * 256 + threadIdx.x;   // < 131072
    const int bm  = gid >> 12;
    const int j   = (gid >> 5) & 127;
    const int d   = gid & 31;
    const int iN  = (int)(x_size[bm >> 3] + 0.5f);
    if (j >= iN) { out[gid] = 0.f; return; }

    const int nig = (iN + 15) >> 4;                   // valid i-groups (4..8)
    const int jgp = j >> 6;
    const int jl  = j & 63;
    const size_t pb = ((size_t)(bm * 2 + jgp) * 8) * 2048 + jl * 32 + d;
    float sum = 0.f;
    for (int ig = 0; ig < nig; ++ig) sum += partial[pb + (size_t)ig * 2048];
    out[gid] = sum + b3[0] + x[gid];
}

extern "C" void kernel_launch(void* const* d_in, const int* in_sizes, int n_in,
                              void* d_out, int out_size, void* d_ws, size_t ws_size,
                              hipStream_t stream) {
    const float* x      = (const float*)d_in[0];
    const float* x_size = (const float*)d_in[1];
    const float* W1a    = (const float*)d_in[2];
    const float* b1a    = (const float*)d_in[3];
    const float* W1b    = (const float*)d_in[4];
    const float* b1b    = (const float*)d_in[5];
    const float* W2a    = (const float*)d_in[6];
    const float* b2a    = (const float*)d_in[7];
    const float* W2b    = (const float*)d_in[8];
    const float* b2b    = (const float*)d_in[9];
    const float* w3     = (const float*)d_in[10];
    const float* b3     = (const float*)d_in[11];
    float* out = (float*)d_out;

    float* ws      = (float*)d_ws;
    float* x1g     = ws;                       // 131072
    float* A1g     = x1g + (size_t)BMC * ND;   // 262144
    float* A2r     = A1g + (size_t)BMC * NK;   // 262144
    float* v2g     = A2r + (size_t)BMC * NK;   // 64
    float* c3g     = v2g + KKC;                // 1 (+63 pad)
    float* partial = c3g + 64;                 // 512*2048 = 1048576 (4 MB)

    mlp_kernel<<<BMC * 16, 256, 0, stream>>>(x, x_size,
        W1a, b1a, W1b, b1b, W2a, b2a, W2b, b2b, w3,
        x1g, A1g, A2r, v2g, c3g);
    pair_kernel<<<BMC * 16, 256, 0, stream>>>(x_size, A1g, A2r, x1g, v2g, c3g, partial);
    final_kernel<<<512, 256, 0, stream>>>(x, x_size, b3, partial, out);
}